// Round 7
// baseline (109.028 us; speedup 1.0000x reference)
//
#include <hip/hip_runtime.h>

#define BATCH 8
#define NPTS 4096
#define KSEL 6          // K_NN + 1
#define ALPHA 1.05f
#define NSEG 16         // candidate-scan split (one wave each)
#define SEGLEN (NPTS / NSEG)    // 256
#define TPB 1024
#define PPB 128                 // query points per block (2 per thread)
#define NTILES (NPTS / PPB)     // 32

typedef __attribute__((ext_vector_type(2))) float f32x2;

// --- single-inst 3-operand selection ops ---
static __device__ __forceinline__ unsigned min3u(unsigned a, unsigned b, unsigned c) {
  unsigned d;
  asm("v_min3_u32 %0, %1, %2, %3" : "=v"(d) : "v"(a), "v"(b), "v"(c));
  return d;
}
static __device__ __forceinline__ unsigned med3u(unsigned a, unsigned b, unsigned c) {
  unsigned d;
  asm("v_med3_u32 %0, %1, %2, %3" : "=v"(d) : "v"(a), "v"(b), "v"(c));
  return d;
}
static __device__ __forceinline__ unsigned max3u(unsigned a, unsigned b, unsigned c) {
  unsigned d;
  asm("v_max3_u32 %0, %1, %2, %3" : "=v"(d) : "v"(a), "v"(b), "v"(c));
  return d;
}
static __device__ __forceinline__ unsigned umn(unsigned a, unsigned b) { return a < b ? a : b; }
static __device__ __forceinline__ unsigned umx(unsigned a, unsigned b) { return a > b ? a : b; }

// --- packed fp32 (VOP3P): 2 independent fp32 ops per instruction ---
static __device__ __forceinline__ f32x2 pk_mul(f32x2 a, f32x2 b) {
  f32x2 d;
  asm("v_pk_mul_f32 %0, %1, %2" : "=v"(d) : "v"(a), "v"(b));
  return d;
}
static __device__ __forceinline__ f32x2 pk_fma(f32x2 a, f32x2 b, f32x2 c) {
  f32x2 d;
  asm("v_pk_fma_f32 %0, %1, %2, %3" : "=v"(d) : "v"(a), "v"(b), "v"(c));
  return d;
}

#define FINF 0x7F800000u

// Fused branchless insert of two candidates into sorted m[0..5]
// (bit-identical to sequential insert; absmax 0.0 since R2).
static __device__ __forceinline__ void insert2(unsigned m[KSEL], unsigned tA, unsigned tB) {
#pragma unroll
  for (int k = 0; k < KSEL - 1; ++k) {
    const unsigned mk = m[k];
    m[k] = min3u(mk, tA, tB);
    const unsigned nA = med3u(mk, tA, tB);
    const unsigned nB = max3u(mk, tA, tB);
    tA = nA;
    tB = nB;
  }
  m[KSEL - 1] = min3u(m[KSEL - 1], tA, tB);
}

struct __align__(16) pkpair { f32x2 lo, hi; };

// ---------------------------------------------------------------------------
// Kernel 1: per-point mean 5-NN squared distance.
// grid = 256 blocks (1/CU), block = 1024 threads (16 waves), 2 query points
// per thread (PPB=128). R6 post-mortem: scan was LDS-issue-bound (4
// ds_read_b128/iter x 8192/CU x 12cyc ~= 41us). Fix: each candidate read now
// feeds 128 points (2/thread), and norms array dropped (diff formulation,
// bit-identical to R2-R5) -> 3 reads/iter, ~15us LDS per CU.
// ---------------------------------------------------------------------------
__global__ __launch_bounds__(TPB, 4) void knn_value_kernel(const float* __restrict__ pc,
                                                           float* __restrict__ value,
                                                           float* __restrict__ out) {
  __shared__ union __align__(16) {
    struct { float xs[NPTS]; float ys[NPTS]; float zs[NPTS]; } s;  // 48 KB
    unsigned cand[NSEG][PPB][KSEL];                                // 48 KB
  } sh;

  const int tid  = threadIdx.x;
  const int lane = tid & 63;
  const int seg  = __builtin_amdgcn_readfirstlane(tid >> 6);  // wave-uniform
  const int b    = blockIdx.x >> 5;   // batch
  const int tile = blockIdx.x & 31;   // 32 tiles of 128 points

  if (blockIdx.x == 0 && tid == 0) out[0] = 0.0f;  // stats kernel accumulates

  const float* __restrict__ base = pc + (size_t)b * (NPTS * 3);

  // Stage SoA. Thread t handles points 4t..4t+3 = float4s 3t..3t+2.
  {
    const float4* __restrict__ b4 = (const float4*)base;
    const float4 q0 = b4[tid * 3 + 0];   // x0 y0 z0 x1
    const float4 q1 = b4[tid * 3 + 1];   // y1 z1 x2 y2
    const float4 q2 = b4[tid * 3 + 2];   // z2 x3 y3 z3
    const int p0 = tid * 4;
    sh.s.xs[p0 + 0] = q0.x; sh.s.ys[p0 + 0] = q0.y; sh.s.zs[p0 + 0] = q0.z;
    sh.s.xs[p0 + 1] = q0.w; sh.s.ys[p0 + 1] = q1.x; sh.s.zs[p0 + 1] = q1.y;
    sh.s.xs[p0 + 2] = q1.z; sh.s.ys[p0 + 2] = q1.w; sh.s.zs[p0 + 2] = q2.x;
    sh.s.xs[p0 + 3] = q2.y; sh.s.ys[p0 + 3] = q2.z; sh.s.zs[p0 + 3] = q2.w;
  }
  __syncthreads();

  const int i0 = tile * PPB + lane;   // query point A
  const int i1 = i0 + 64;             // query point B
  const float x0 = sh.s.xs[i0], y0 = sh.s.ys[i0], z0 = sh.s.zs[i0];
  const float x1 = sh.s.xs[i1], y1 = sh.s.ys[i1], z1 = sh.s.zs[i1];
  const f32x2 x0p = {x0, x0}, y0p = {y0, y0}, z0p = {z0, z0};
  const f32x2 x1p = {x1, x1}, y1p = {y1, y1}, z1p = {z1, z1};
  const f32x2 neg1 = {-1.0f, -1.0f};

  unsigned m0[KSEL], m1[KSEL];
#pragma unroll
  for (int k = 0; k < KSEL; ++k) { m0[k] = FINF; m1[k] = FINF; }

  const int j0 = seg * SEGLEN;
#pragma unroll 2
  for (int jj = 0; jj < SEGLEN; jj += 4) {
    // 4 wave-uniform candidates: 3x ds_read_b128 broadcast
    const pkpair cx = *(const pkpair*)&sh.s.xs[j0 + jj];
    const pkpair cy = *(const pkpair*)&sh.s.ys[j0 + jj];
    const pkpair cz = *(const pkpair*)&sh.s.zs[j0 + jj];

    // point A: dx = fma(cx,-1,xi) == xi-cx bitwise; d = dx^2 fma dy fma dz
    {
      const f32x2 dxl = pk_fma(cx.lo, neg1, x0p), dxh = pk_fma(cx.hi, neg1, x0p);
      const f32x2 dyl = pk_fma(cy.lo, neg1, y0p), dyh = pk_fma(cy.hi, neg1, y0p);
      const f32x2 dzl = pk_fma(cz.lo, neg1, z0p), dzh = pk_fma(cz.hi, neg1, z0p);
      f32x2 dl = pk_mul(dxl, dxl), dh = pk_mul(dxh, dxh);
      dl = pk_fma(dyl, dyl, dl);  dh = pk_fma(dyh, dyh, dh);
      dl = pk_fma(dzl, dzl, dl);  dh = pk_fma(dzh, dzh, dh);
      insert2(m0, __float_as_uint(dl.x), __float_as_uint(dl.y));
      insert2(m0, __float_as_uint(dh.x), __float_as_uint(dh.y));
    }
    // point B: reuses the same candidate registers
    {
      const f32x2 dxl = pk_fma(cx.lo, neg1, x1p), dxh = pk_fma(cx.hi, neg1, x1p);
      const f32x2 dyl = pk_fma(cy.lo, neg1, y1p), dyh = pk_fma(cy.hi, neg1, y1p);
      const f32x2 dzl = pk_fma(cz.lo, neg1, z1p), dzh = pk_fma(cz.hi, neg1, z1p);
      f32x2 dl = pk_mul(dxl, dxl), dh = pk_mul(dxh, dxh);
      dl = pk_fma(dyl, dyl, dl);  dh = pk_fma(dyh, dyh, dh);
      dl = pk_fma(dzl, dzl, dl);  dh = pk_fma(dzh, dzh, dh);
      insert2(m1, __float_as_uint(dl.x), __float_as_uint(dl.y));
      insert2(m1, __float_as_uint(dh.x), __float_as_uint(dh.y));
    }
  }
  __syncthreads();  // everyone done reading the stage buffer

#pragma unroll
  for (int k = 0; k < KSEL; ++k) {
    sh.cand[seg][lane][k]      = m0[k];
    sh.cand[seg][lane + 64][k] = m1[k];
  }
  __syncthreads();

  // Tree-merge the 16 sorted lists per point: 8,4,2,1 pairwise merges.
  for (int st = 1; st < NSEG; st <<= 1) {
    const int pairs = NSEG / (2 * st);
    if (tid < pairs * PPB) {
      const int q = tid >> 7;        // pair index
      const int p = tid & (PPB - 1); // point within tile
      unsigned* A = &sh.cand[2 * st * q][p][0];
      const unsigned* B = &sh.cand[2 * st * q + st][p][0];
      unsigned mm[KSEL];
#pragma unroll
      for (int k = 0; k < KSEL; ++k) mm[k] = A[k];
#pragma unroll
      for (int k = 0; k < KSEL; ++k) {
        unsigned t = B[k];
#pragma unroll
        for (int u = 0; u < KSEL - 1; ++u) {
          const unsigned lo = umn(mm[u], t);
          t = umx(mm[u], t);
          mm[u] = lo;
        }
        mm[KSEL - 1] = umn(mm[KSEL - 1], t);
      }
#pragma unroll
      for (int k = 0; k < KSEL; ++k) A[k] = mm[k];
    }
    __syncthreads();
  }

  // drop the smallest (self-distance 0), mean of remaining 5
  if (tid < PPB) {
    float s5 = 0.f;
#pragma unroll
    for (int k = 1; k < KSEL; ++k) s5 += __uint_as_float(sh.cand[0][tid][k]);
    value[b * NPTS + tile * PPB + tid] = s5 * 0.2f;
  }
}

// ---------------------------------------------------------------------------
// Kernel 2: per-batch mean / unbiased std / threshold / masked mean * weight,
// then atomicAdd of loss*(1/BATCH) into out (zeroed by kernel 1).
// ---------------------------------------------------------------------------
__global__ __launch_bounds__(256) void stats_kernel(const float* __restrict__ value,
                                                    const float* __restrict__ weights,
                                                    float* __restrict__ out) {
  __shared__ float red[256];
  const int b   = blockIdx.x;
  const int tid = threadIdx.x;
  const float* __restrict__ v = value + b * NPTS;

  float s = 0.f;
  for (int j = tid; j < NPTS; j += 256) s += v[j];
  red[tid] = s;
  __syncthreads();
  for (int off = 128; off > 0; off >>= 1) {
    if (tid < off) red[tid] += red[tid + off];
    __syncthreads();
  }
  const float mean = red[0] * (1.0f / NPTS);
  __syncthreads();

  float s2 = 0.f;
  for (int j = tid; j < NPTS; j += 256) {
    const float d = v[j] - mean;
    s2 += d * d;
  }
  red[tid] = s2;
  __syncthreads();
  for (int off = 128; off > 0; off >>= 1) {
    if (tid < off) red[tid] += red[tid + off];
    __syncthreads();
  }
  const float thr = mean + ALPHA * sqrtf(red[0] * (1.0f / (NPTS - 1)));
  __syncthreads();

  float s3 = 0.f;
  for (int j = tid; j < NPTS; j += 256) {
    const float vv = v[j];
    if (vv > thr) s3 += vv;
  }
  red[tid] = s3;
  __syncthreads();
  for (int off = 128; off > 0; off >>= 1) {
    if (tid < off) red[tid] += red[tid + off];
    __syncthreads();
  }
  if (tid == 0) {
    atomicAdd(out, red[0] * (1.0f / NPTS) * weights[b] * (1.0f / BATCH));
  }
}

extern "C" void kernel_launch(void* const* d_in, const int* in_sizes, int n_in,
                              void* d_out, int out_size, void* d_ws, size_t ws_size,
                              hipStream_t stream) {
  const float* pc      = (const float*)d_in[0];   // [8,4096,3] f32
  const float* weights = (const float*)d_in[1];   // [8] f32
  float* out   = (float*)d_out;                   // scalar f32
  float* value = (float*)d_ws;                    // [8*4096] f32

  knn_value_kernel<<<dim3(BATCH * NTILES), dim3(TPB), 0, stream>>>(pc, value, out);
  stats_kernel<<<dim3(BATCH), dim3(256), 0, stream>>>(value, weights, out);
}